// Round 4
// baseline (1365.491 us; speedup 1.0000x reference)
//
#include <hip/hip_runtime.h>

// 2-layer tanh RNN (B=4096, T=512, D=30) + MLP head (30->15->15->1), fp32.
//
// One wave per batch chain, block=64 -> 4096 blocks. Lane roles:
//   lanes 0..29  : rows of layer-1 state (h1), W1 rows (j<15), W2 rows (16..30)
//   lanes 32..61 : rows of layer-2 state (h2)
// Dual-packed weight arrays so each broadcast-dot serves two matvecs:
//   aw: lower = Whh1 row, upper = Wih2 row      (phase 1, broadcast h1)
//   bw: lower = W1|W2 rows, upper = Whh2 row    (phase 2/3, broadcast h2/v1)
// Broadcast via v_readlane -> SGPR operand of v_fma. No LDS.
//
// R3 lesson: pre-loop PIN left VGPR_Count=52 -> weights lived in AGPR spills /
// in-loop reloads (~90 extra ops/step). Fix: VOLATILE pins INSIDE the loop
// (can't be hoisted) force per-iteration arch-VGPR residency; x prefetched
// distance-2 in SGPR ping-pong buffers to cover HBM latency.

namespace {
constexpr int T = 512;
constexpr int D = 30;   // hidden size
constexpr int H = 15;   // head hidden size

// tanh(x) = 1 - 2/(exp(2x)+1): NaN-free at +/-inf, ~1e-6 abs err.
__device__ __forceinline__ float fast_tanh(float x) {
  float e = __expf(2.0f * x);
  return 1.0f - 2.0f * __builtin_amdgcn_rcpf(e + 1.0f);
}

// Broadcast lane `lane`'s value to all lanes via v_readlane (SGPR result).
__device__ __forceinline__ float bcast(float v, int lane) {
  return __int_as_float(__builtin_amdgcn_readlane(__float_as_int(v), lane));
}

// Volatile in-loop pin: forces the value into an arch VGPR at this point of
// every iteration; compiles to zero instructions if the RA complies.
#define PINV(v) asm volatile("" : "+v"(v))

// Scalar load: keeps wave-uniform x values in SGPRs (free if the compiler
// already chose s_load; inserts readfirstlane otherwise).
__device__ __forceinline__ float sload(const float* p) {
  float v = *p;
  asm("" : "+s"(v));
  return v;
}
}  // namespace

__global__ __launch_bounds__(64, 3) void rnn_head_fused(
    const float* __restrict__ x,
    const float* __restrict__ Wih1, const float* __restrict__ Whh1,
    const float* __restrict__ bih1, const float* __restrict__ bhh1,
    const float* __restrict__ Wih2, const float* __restrict__ Whh2,
    const float* __restrict__ bih2, const float* __restrict__ bhh2,
    const float* __restrict__ W1, const float* __restrict__ b1,
    const float* __restrict__ W2, const float* __restrict__ b2,
    const float* __restrict__ W3, const float* __restrict__ b3,
    float* __restrict__ out) {
  const int j = threadIdx.x;           // 0..63
  const bool lo = (j < 32);
  const int ju = j & 31;
  const int r = (ju < D) ? ju : (D - 1);  // clamped row index 0..29

  // ---- per-lane weight rows ----
  float dk[D], aw[D], bw[D];
  {
    const float* Dr = Wih1 + r * D;
    const float* Ar = (lo ? Whh1 : Wih2) + r * D;
#pragma unroll
    for (int k = 0; k < D; ++k) {
      dk[k] = Dr[k];
      aw[k] = Ar[k];
    }
#pragma unroll
    for (int k = 0; k < D; ++k) {
      float v;
      if (!lo)
        v = Whh2[r * D + k];
      else if (j < H)
        v = W1[j * D + k];                 // lanes 0..14: W1 rows (v1)
      else if (j >= 16 && j < 31 && k < H)
        v = W2[(j - 16) * H + k];          // lanes 16..30: W2 rows (v2)
      else
        v = 0.0f;                          // lanes 15, 31: dead
      bw[k] = v;
    }
  }

  float biasA = lo ? (bih1[r] + bhh1[r]) : (bih2[r] + bhh2[r]);
  float biasB = (j < H) ? b1[j] : ((j >= 16 && j < 31) ? b2[j - 16] : 0.0f);
  const bool mid = (j >= 16) && (j < 31);  // lanes holding v2
  float w3v = mid ? W3[j - 16] : 0.0f;
  const float sb3 = b3[0];

  const float* xr = x + (long)blockIdx.x * (T * D);
  float* outp = out + (long)blockIdx.x * T;

  // x ping-pong buffers in SGPRs, prefetch distance 2 (~2 steps of latency)
  float sxA[D], sxB[D];
#pragma unroll
  for (int k = 0; k < D; ++k) sxA[k] = sload(xr + k);
#pragma unroll
  for (int k = 0; k < D; ++k) sxB[k] = sload(xr + D + k);

  float rec1 = 0.0f;  // Whh1*h1_{t-1}, valid on lower lanes
  float rec2 = 0.0f;  // Whh2*h2_{t-1}, valid on upper lanes

  auto step = [&](float(&sx)[D], int tpre) -> float {
    // ---- layer-1 input projection: Wih1[r,:] . x_t (SGPR operands) ----
    float xa = biasA, xb = rec1;  // rec1 garbage on upper lanes; h1 unused there
#pragma unroll
    for (int k = 0; k < D; ++k) {
      if (k & 1)
        xb = fmaf(dk[k], sx[k], xb);
      else
        xa = fmaf(dk[k], sx[k], xa);
    }
    const float h1 = fast_tanh(xa + xb);  // valid on lanes 0..29

    // refill this buffer for step tpre (waited on ~2 steps from now)
#pragma unroll
    for (int k = 0; k < D; ++k) sx[k] = sload(xr + (long)tpre * D + k);

    // ---- phase 1: broadcast h1; lower->rec1_next, upper->layer2 in-proj ----
    float p1a = 0.0f, p1b = 0.0f;
#pragma unroll
    for (int k = 0; k < D; ++k) {
      const float s = bcast(h1, k);
      if (k & 1)
        p1b = fmaf(aw[k], s, p1b);
      else
        p1a = fmaf(aw[k], s, p1a);
    }
    const float p1 = p1a + p1b;
    rec1 = p1;
    const float h2 = fast_tanh(p1 + biasA + rec2);  // valid on lanes 32..61

    // ---- phase 2: broadcast h2; lower->u1 (b1 folded), upper->rec2_next ----
    float p2a = biasB, p2b = 0.0f;  // biasB==0 on upper: rec2 stays pure
#pragma unroll
    for (int k = 0; k < D; ++k) {
      const float s = bcast(h2, 32 + k);
      if (k & 1)
        p2b = fmaf(bw[k], s, p2b);
      else
        p2a = fmaf(bw[k], s, p2a);
    }
    const float p2 = p2a + p2b;
    rec2 = p2;
    const float v1 = fast_tanh(p2);  // valid on lanes 0..14

    // ---- phase 3: broadcast v1; lanes 16..30 -> u2 (b2 folded) ----
    float p3a = biasB, p3b = 0.0f;
#pragma unroll
    for (int k = 0; k < H; ++k) {
      const float s = bcast(v1, k);
      if (k & 1)
        p3b = fmaf(bw[k], s, p3b);
      else
        p3a = fmaf(bw[k], s, p3a);
    }
    const float v2 = fast_tanh(p3a + p3b);  // valid on lanes 16..30

    // ---- head layer 3: reduce W3.v2 within the aligned 16-group 16..31 ----
    float pv = mid ? (w3v * v2) : 0.0f;  // cndmask kills garbage-lane NaNs
    pv += __shfl_xor(pv, 8, 16);
    pv += __shfl_xor(pv, 4, 16);
    pv += __shfl_xor(pv, 2, 16);
    pv += __shfl_xor(pv, 1, 16);
    return pv;  // result on lanes 16..31
  };

  for (int t = 0; t < T; t += 2) {
    const float pA = step(sxA, (t + 2 < T) ? (t + 2) : (T - 1));
    const float pB = step(sxB, (t + 3 < T) ? (t + 3) : (T - 1));
    if (j == 16) {
      float2 o;
      o.x = pA + sb3;
      o.y = pB + sb3;
      *(float2*)(outp + t) = o;  // outp+t is 8B aligned (t even)
    }
    // Volatile in-loop pins: weights/biases must sit in arch VGPRs every
    // iteration (zero instructions when the RA complies; defeats AGPR
    // spilling and load sinking).
#pragma unroll
    for (int k = 0; k < D; ++k) {
      PINV(dk[k]);
      PINV(aw[k]);
      PINV(bw[k]);
    }
    PINV(biasA);
    PINV(biasB);
    PINV(w3v);
  }
}

extern "C" void kernel_launch(void* const* d_in, const int* in_sizes, int n_in,
                              void* d_out, int out_size, void* d_ws,
                              size_t ws_size, hipStream_t stream) {
  const float* x = (const float*)d_in[0];
  const float* Wih1 = (const float*)d_in[1];
  const float* Whh1 = (const float*)d_in[2];
  const float* bih1 = (const float*)d_in[3];
  const float* bhh1 = (const float*)d_in[4];
  const float* Wih2 = (const float*)d_in[5];
  const float* Whh2 = (const float*)d_in[6];
  const float* bih2 = (const float*)d_in[7];
  const float* bhh2 = (const float*)d_in[8];
  const float* W1 = (const float*)d_in[9];
  const float* b1 = (const float*)d_in[10];
  const float* W2 = (const float*)d_in[11];
  const float* b2 = (const float*)d_in[12];
  const float* W3 = (const float*)d_in[13];
  const float* b3 = (const float*)d_in[14];

  const int B = in_sizes[0] / (T * D);  // 4096 chains, one wave each
  dim3 grid(B), block(64);
  hipLaunchKernelGGL(rnn_head_fused, grid, block, 0, stream, x, Wih1, Whh1,
                     bih1, bhh1, Wih2, Whh2, bih2, bhh2, W1, b1, W2, b2, W3, b3,
                     (float*)d_out);
}

// Round 5
// 1267.557 us; speedup vs baseline: 1.0773x; 1.0773x over previous
//
#include <hip/hip_runtime.h>

// 2-layer tanh RNN (B=4096, T=512, D=30) + MLP head (30->15->15->1), fp32.
//
// One wave per batch chain, block=64 -> 4096 blocks (12 waves/CU at bounds
// (64,3)). ALL operands flow through readlane-broadcast dots; per-lane data:
//   x_t   : lane k holds x_t[k]           (1 VGPR + 1 prefetch VGPR)
//   dk    : Wih1 row r (all lanes)        -> phase 0 (broadcast x)
//   aw    : lower=Whh1 row, upper=Wih2 row-> phase 1 (broadcast h1)
//   bw    : lower=W1|W2 rows, upper=Whh2  -> phase 2/3 (broadcast h2/v1)
// Live set ~120 VGPRs < 170 target, so the RA has no reason to AGPR-spill
// (R2-R4 lesson: pressure > target => v_accvgpr spills that VGPR_Count=52
// masked; in-loop asm-volatile pins fence the scheduler => never again).

namespace {
constexpr int T = 512;
constexpr int D = 30;   // hidden size
constexpr int H = 15;   // head hidden size

// tanh(x) = 1 - 2/(exp(2x)+1): NaN-free at +/-inf, ~1e-6 abs err.
__device__ __forceinline__ float fast_tanh(float x) {
  float e = __expf(2.0f * x);
  return 1.0f - 2.0f * __builtin_amdgcn_rcpf(e + 1.0f);
}

// Broadcast lane `lane`'s value (SGPR result, scalar operand of v_fma).
__device__ __forceinline__ float bcast(float v, int lane) {
  return __int_as_float(__builtin_amdgcn_readlane(__float_as_int(v), lane));
}

// Non-volatile pre-loop pin: value must materialize in an arch VGPR here;
// not a scheduling fence, not hoistable into the loop, not rematerializable.
#define PIN(v) asm("" : "+v"(v))
}  // namespace

__global__ __launch_bounds__(64, 3) void rnn_head_fused(
    const float* __restrict__ x,
    const float* __restrict__ Wih1, const float* __restrict__ Whh1,
    const float* __restrict__ bih1, const float* __restrict__ bhh1,
    const float* __restrict__ Wih2, const float* __restrict__ Whh2,
    const float* __restrict__ bih2, const float* __restrict__ bhh2,
    const float* __restrict__ W1, const float* __restrict__ b1,
    const float* __restrict__ W2, const float* __restrict__ b2,
    const float* __restrict__ W3, const float* __restrict__ b3,
    float* __restrict__ out) {
  const int j = threadIdx.x;           // 0..63
  const bool lo = (j < 32);
  const int ju = j & 31;
  const int r = (ju < D) ? ju : (D - 1);  // clamped row index 0..29

  // ---- per-lane weight rows ----
  float dk[D], aw[D], bw[D];
  {
    const float* Dr = Wih1 + r * D;
    const float* Ar = (lo ? Whh1 : Wih2) + r * D;
#pragma unroll
    for (int k = 0; k < D; ++k) {
      dk[k] = Dr[k];
      aw[k] = Ar[k];
    }
#pragma unroll
    for (int k = 0; k < D; ++k) {
      float v;
      if (!lo)
        v = Whh2[r * D + k];
      else if (j < H)
        v = W1[j * D + k];                 // lanes 0..14: W1 rows (-> v1)
      else if (j >= 16 && j < 31 && k < H)
        v = W2[(j - 16) * H + k];          // lanes 16..30: W2 rows (-> v2)
      else
        v = 0.0f;                          // lanes 15, 31: dead
      bw[k] = v;
    }
  }
#pragma unroll
  for (int k = 0; k < D; ++k) {
    PIN(dk[k]);
    PIN(aw[k]);
    PIN(bw[k]);
  }

  float biasA = lo ? (bih1[r] + bhh1[r]) : (bih2[r] + bhh2[r]);
  float biasB = (j < H) ? b1[j] : ((j >= 16 && j < 31) ? b2[j - 16] : 0.0f);
  const bool mid = (j >= 16) && (j < 31);  // lanes holding v2
  float w3v = mid ? W3[j - 16] : 0.0f;
  const float sb3 = b3[0];
  PIN(biasA);
  PIN(biasB);
  PIN(w3v);

  const float* xr = x + (long)blockIdx.x * (T * D);
  float* outp = out + (long)blockIdx.x * T;
  const int cj = (ju < D) ? ju : (D - 1);  // x lane-slot (clamped; dups ok)

  // x ping-pong: lane k holds x_t[k]; prefetch distance 2 (~1000 cyc slack)
  float xvA = xr[cj];      // t = 0
  float xvB = xr[D + cj];  // t = 1

  float rec1 = 0.0f;  // Whh1*h1_{t-1}, valid on lower lanes
  float rec2 = 0.0f;  // Whh2*h2_{t-1}, valid on upper lanes

  auto step = [&](float& xv, int tpre) -> float {
    // ---- phase 0: broadcast x_t; dk dot -> xw1[r] (biasA, rec1 folded) ----
    float a0 = biasA, a1 = rec1, a2 = 0.0f, a3 = 0.0f;
#pragma unroll
    for (int k = 0; k < D; ++k) {
      const float s = bcast(xv, k);
      if ((k & 3) == 0)
        a0 = fmaf(dk[k], s, a0);
      else if ((k & 3) == 1)
        a1 = fmaf(dk[k], s, a1);
      else if ((k & 3) == 2)
        a2 = fmaf(dk[k], s, a2);
      else
        a3 = fmaf(dk[k], s, a3);
    }
    const float h1 = fast_tanh((a0 + a1) + (a2 + a3));  // lanes 0..29

    // refill this buffer for step tpre (consumed 2 steps from now)
    xv = xr[(long)tpre * D + cj];

    // ---- phase 1: broadcast h1; lower->rec1_next, upper->layer2 in-proj ----
    float p0 = 0.0f, p1 = 0.0f, p2 = 0.0f, p3 = 0.0f;
#pragma unroll
    for (int k = 0; k < D; ++k) {
      const float s = bcast(h1, k);
      if ((k & 3) == 0)
        p0 = fmaf(aw[k], s, p0);
      else if ((k & 3) == 1)
        p1 = fmaf(aw[k], s, p1);
      else if ((k & 3) == 2)
        p2 = fmaf(aw[k], s, p2);
      else
        p3 = fmaf(aw[k], s, p3);
    }
    const float P1 = (p0 + p1) + (p2 + p3);
    rec1 = P1;                                      // meaningful on lower
    const float h2 = fast_tanh(P1 + biasA + rec2);  // lanes 32..61

    // ---- phase 2: broadcast h2; lower->u1 (b1 folded), upper->rec2_next ----
    float q0 = biasB, q1 = 0.0f, q2 = 0.0f, q3 = 0.0f;  // biasB==0 on upper
#pragma unroll
    for (int k = 0; k < D; ++k) {
      const float s = bcast(h2, 32 + k);
      if ((k & 3) == 0)
        q0 = fmaf(bw[k], s, q0);
      else if ((k & 3) == 1)
        q1 = fmaf(bw[k], s, q1);
      else if ((k & 3) == 2)
        q2 = fmaf(bw[k], s, q2);
      else
        q3 = fmaf(bw[k], s, q3);
    }
    const float P2 = (q0 + q1) + (q2 + q3);
    rec2 = P2;                       // meaningful on upper
    const float v1 = fast_tanh(P2);  // lanes 0..14

    // ---- phase 3: broadcast v1; lanes 16..30 -> u2 (b2 folded) ----
    float u0 = biasB, u1 = 0.0f, u2 = 0.0f, u3 = 0.0f;
#pragma unroll
    for (int k = 0; k < H; ++k) {
      const float s = bcast(v1, k);
      if ((k & 3) == 0)
        u0 = fmaf(bw[k], s, u0);
      else if ((k & 3) == 1)
        u1 = fmaf(bw[k], s, u1);
      else if ((k & 3) == 2)
        u2 = fmaf(bw[k], s, u2);
      else
        u3 = fmaf(bw[k], s, u3);
    }
    const float v2 = fast_tanh((u0 + u1) + (u2 + u3));  // lanes 16..30

    // ---- head layer 3: reduce W3.v2 within the aligned group [16,31] ----
    float pv = mid ? (w3v * v2) : 0.0f;  // cndmask kills garbage-lane values
    pv += __shfl_xor(pv, 8, 16);
    pv += __shfl_xor(pv, 4, 16);
    pv += __shfl_xor(pv, 2, 16);
    pv += __shfl_xor(pv, 1, 16);
    return pv;  // valid on lanes 16..31
  };

  for (int t = 0; t < T; t += 2) {
    const float pA = step(xvA, (t + 2 < T) ? (t + 2) : (T - 1));
    const float pB = step(xvB, (t + 3 < T) ? (t + 3) : (T - 1));
    if (j == 16) {
      float2 o;
      o.x = pA + sb3;
      o.y = pB + sb3;
      *(float2*)(outp + t) = o;  // outp+t is 8B aligned (t even)
    }
  }
}

extern "C" void kernel_launch(void* const* d_in, const int* in_sizes, int n_in,
                              void* d_out, int out_size, void* d_ws,
                              size_t ws_size, hipStream_t stream) {
  const float* x = (const float*)d_in[0];
  const float* Wih1 = (const float*)d_in[1];
  const float* Whh1 = (const float*)d_in[2];
  const float* bih1 = (const float*)d_in[3];
  const float* bhh1 = (const float*)d_in[4];
  const float* Wih2 = (const float*)d_in[5];
  const float* Whh2 = (const float*)d_in[6];
  const float* bih2 = (const float*)d_in[7];
  const float* bhh2 = (const float*)d_in[8];
  const float* W1 = (const float*)d_in[9];
  const float* b1 = (const float*)d_in[10];
  const float* W2 = (const float*)d_in[11];
  const float* b2 = (const float*)d_in[12];
  const float* W3 = (const float*)d_in[13];
  const float* b3 = (const float*)d_in[14];

  const int B = in_sizes[0] / (T * D);  // 4096 chains, one wave each
  dim3 grid(B), block(64);
  hipLaunchKernelGGL(rnn_head_fused, grid, block, 0, stream, x, Wih1, Whh1,
                     bih1, bhh1, Wih2, Whh2, bih2, bhh2, W1, b1, W2, b2, W3, b3,
                     (float*)d_out);
}